// Round 5
// baseline (743.818 us; speedup 1.0000x reference)
//
#include <hip/hip_runtime.h>

#define B   16384
#define F_S 26
#define F_D 13
#define V   100000
#define D   64

// 4 rows per wave: 16 lanes per row, each lane loads float4 (16B) -> one
// 1KB transaction per feature-gather instruction (coalescing sweet spot).
// Block = 256 threads = 4 waves = 16 rows. Grid = B/16 = 1024 blocks.
__global__ __launch_bounds__(256) void fm_kernel(
    const int*   __restrict__ sparse_idx,    // [B, F_S]
    const float* __restrict__ dense,         // [B, F_D]
    const float* __restrict__ emb_lin,       // [F_S, V]
    const float* __restrict__ emb_v,         // [F_S, V, D]
    const float* __restrict__ lin_dense_W,   // [1, F_D]
    const float* __restrict__ lin_dense_b,   // [1]
    const float* __restrict__ dense_arch_W,  // [D, F_D]
    const float* __restrict__ dense_arch_b,  // [D]
    const float* __restrict__ bias,          // [1, 1]
    float*       __restrict__ out)           // [B]
{
    __shared__ int sidx[16 * F_S];           // 416 ints, 1.6 KB

    // --- stage this block's 16x26 indices with 2 coalesced loads ---
    const int iblock = blockIdx.x * 16 * F_S;
    sidx[threadIdx.x] = sparse_idx[iblock + threadIdx.x];
    if (threadIdx.x < 16 * F_S - 256)
        sidx[256 + threadIdx.x] = sparse_idx[iblock + 256 + threadIdx.x];
    __syncthreads();

    const int wave = threadIdx.x >> 6;
    const int lane = threadIdx.x & 63;
    const int sub  = lane >> 4;              // row within wave's quad (0..3)
    const int t    = lane & 15;              // float4 slot: dims 4t..4t+3
    const int rowl = wave * 4 + sub;         // row within block (0..15)
    const int row  = blockIdx.x * 16 + rowl; // global row

    // --- dense features for my row (same addr across 16-lane group -> bcast)
    float dvals[F_D];
#pragma unroll
    for (int j = 0; j < F_D; ++j) dvals[j] = dense[row * F_D + j];

    // --- v_d dims 4t..4t+3: vd[i] = W[4t+i,:] . dvals + b[4t+i] (L1-resident W)
    float4 S;
    float  sq = 0.f;
    {
        float vd[4];
#pragma unroll
        for (int i = 0; i < 4; ++i) {
            float acc = dense_arch_b[4 * t + i];
#pragma unroll
            for (int j = 0; j < F_D; ++j)
                acc = fmaf(dense_arch_W[(4 * t + i) * F_D + j], dvals[j], acc);
            vd[i] = acc;
            sq = fmaf(acc, acc, sq);
        }
        S = make_float4(vd[0], vd[1], vd[2], vd[3]);
    }

    // --- 26 float4 gathers from the 665MB table (dominant cost) ---
    const float4* __restrict__ emb_v4 = (const float4*)emb_v;
#pragma unroll
    for (int f = 0; f < F_S; ++f) {
        int idxf = sidx[rowl * F_S + f];     // LDS broadcast per 16-lane group
        float4 v = emb_v4[((size_t)f * V + (size_t)idxf) * 16 + t];
        S.x += v.x; S.y += v.y; S.z += v.z; S.w += v.w;
        sq = fmaf(v.x, v.x, sq);
        sq = fmaf(v.y, v.y, sq);
        sq = fmaf(v.z, v.z, sq);
        sq = fmaf(v.w, v.w, sq);
    }

    // --- per-lane partial: second-order over my 4 dims ---
    float part = 0.5f * (S.x * S.x + S.y * S.y + S.z * S.z + S.w * S.w - sq);

    // --- first-order: 26 emb_lin gathers per row spread over 16 lanes (2 rounds)
    {
        int i0 = sidx[rowl * F_S + t];
        part += emb_lin[(size_t)t * V + (size_t)i0];
        if (t < F_S - 16) {
            int i1 = sidx[rowl * F_S + t + 16];
            part += emb_lin[(size_t)(t + 16) * V + (size_t)i1];
        }
    }
    // --- first-order dense: lane t<13 contributes dense[row,t]*W[t] ---
    if (t < F_D)
        part = fmaf(dense[row * F_D + t], lin_dense_W[t], part);

    // --- reduce across the 16 lanes of this row ---
#pragma unroll
    for (int off = 8; off > 0; off >>= 1)
        part += __shfl_xor(part, off);

    if (t == 0)
        out[row] = part + lin_dense_b[0] + bias[0];
}

extern "C" void kernel_launch(void* const* d_in, const int* in_sizes, int n_in,
                              void* d_out, int out_size, void* d_ws, size_t ws_size,
                              hipStream_t stream) {
    const int*   sparse_idx   = (const int*)  d_in[0];
    const float* dense        = (const float*)d_in[1];
    const float* emb_lin      = (const float*)d_in[2];
    const float* emb_v        = (const float*)d_in[3];
    const float* lin_dense_W  = (const float*)d_in[4];
    const float* lin_dense_b  = (const float*)d_in[5];
    const float* dense_arch_W = (const float*)d_in[6];
    const float* dense_arch_b = (const float*)d_in[7];
    const float* bias         = (const float*)d_in[8];
    float*       out          = (float*)d_out;

    fm_kernel<<<dim3(B / 16), dim3(256), 0, stream>>>(
        sparse_idx, dense, emb_lin, emb_v,
        lin_dense_W, lin_dense_b, dense_arch_W, dense_arch_b, bias, out);
}